// Round 13
// baseline (2428.551 us; speedup 1.0000x reference)
//
#include <hip/hip_runtime.h>
#include <hip/hip_bf16.h>

#define NL 6
#define DT 6144
#define DM 768
#define TOK 128

// encode: decode-clone staging + 16B-chunk XOR swizzle (r12 structure)
#define EF 32             // f-rows per block (4 waves x 8 rows staged)
#define EK 256            // k-cols per step (1 KB/row -> contiguous stage16)
#define ENST (DM / EK)    // 3 k-steps

// decode geometry: r9 (in-block i-accumulation, per-j f-split)
#define TD 256
#define NTD 3

// MEASUREMENT ROUND: reps (encode idempotent; decode adds 0 for rep>0)
#define EREP 24
#define DREP 8

using bf16x8 = __attribute__((ext_vector_type(8))) short;
using f32x4  = __attribute__((ext_vector_type(4))) float;

typedef unsigned int u32;
typedef __attribute__((address_space(1))) const u32 gu32;
typedef __attribute__((address_space(3))) u32 lu32;

__device__ __forceinline__ void stage16(const float* g, float* l) {
  __builtin_amdgcn_global_load_lds((gu32*)g, (lu32*)l, 16, 0, 0);
}

__device__ __forceinline__ short f2bf(float f) {
  union { float f; unsigned u; } c; c.f = f;
  unsigned u = c.u;
  u += 0x7fffu + ((u >> 16) & 1u);
  return (short)(u >> 16);
}

// xb = bf16(x)
__global__ void initcvt_k(const float* __restrict__ x, ushort* __restrict__ xb) {
  int idx = blockIdx.x * 256 + threadIdx.x;
  if (idx < NL * TOK * DM) xb[idx] = (ushort)f2bf(x[idx]);
}

// r12 encode, body repeated EREP times (idempotent stores).
__global__ __launch_bounds__(256, 2) void encode_k(
    const ushort* __restrict__ xb, const float* __restrict__ W_enc,
    const float* __restrict__ b_enc, ushort* __restrict__ acts)
{
  __shared__ float lw[2][EF][EK];   // 2 x 32 KB

  const int l  = blockIdx.x / (DT / EF);
  const int f0 = (blockIdx.x % (DT / EF)) * EF;
  const int w    = threadIdx.x >> 6;
  const int lane = threadIdx.x & 63;
  const int lo = lane & 15, hi = lane >> 4;

  const float*  We = W_enc + ((size_t)l * DT + f0) * DM;
  const ushort* Xb = xb + (size_t)l * TOK * DM;

  #pragma unroll 1
  for (int rep = 0; rep < EREP; ++rep) {
    f32x4 acc[2][2];
    #pragma unroll
    for (int mi = 0; mi < 2; ++mi)
      #pragma unroll
      for (int ni = 0; ni < 2; ++ni)
        acc[mi][ni] = f32x4{0.f, 0.f, 0.f, 0.f};

    #pragma unroll
    for (int q = 0; q < 8; ++q) {
      const int row = w * 8 + q;
      const int g   = lane ^ (row & 7);
      stage16(We + (size_t)row * DM + g * 4, &lw[0][row][0]);
    }
    __syncthreads();

    int cur = 0;
    #pragma unroll 1
    for (int st = 0; st < ENST; ++st) {
      if (st + 1 < ENST) {
        #pragma unroll
        for (int q = 0; q < 8; ++q) {
          const int row = w * 8 + q;
          const int g   = lane ^ (row & 7);
          stage16(We + (size_t)row * DM + (st + 1) * EK + g * 4,
                  &lw[cur ^ 1][row][0]);
        }
      }

      const int sw = lo & 7;
      #pragma unroll
      for (int ks = 0; ks < EK / 32; ++ks) {
        bf16x8 a[2], b[2];
        #pragma unroll
        for (int mi = 0; mi < 2; ++mi)
          a[mi] = *(const bf16x8*)(Xb + (size_t)(w * 32 + mi * 16 + lo) * DM
                                   + st * EK + ks * 32 + hi * 8);
        #pragma unroll
        for (int ni = 0; ni < 2; ++ni) {
          const int c0 = (ks * 8 + hi * 2) ^ sw;
          const int c1 = (ks * 8 + hi * 2 + 1) ^ sw;
          const float4 b0 = *(const float4*)&lw[cur][ni * 16 + lo][c0 * 4];
          const float4 b1 = *(const float4*)&lw[cur][ni * 16 + lo][c1 * 4];
          b[ni][0] = f2bf(b0.x); b[ni][1] = f2bf(b0.y);
          b[ni][2] = f2bf(b0.z); b[ni][3] = f2bf(b0.w);
          b[ni][4] = f2bf(b1.x); b[ni][5] = f2bf(b1.y);
          b[ni][6] = f2bf(b1.z); b[ni][7] = f2bf(b1.w);
        }

        #pragma unroll
        for (int mi = 0; mi < 2; ++mi)
          #pragma unroll
          for (int ni = 0; ni < 2; ++ni)
            acc[mi][ni] = __builtin_amdgcn_mfma_f32_16x16x32_bf16(a[mi], b[ni], acc[mi][ni], 0, 0, 0);
      }

      __syncthreads();
      cur ^= 1;
    }

    #pragma unroll
    for (int ni = 0; ni < 2; ++ni) {
      const int f = f0 + ni * 16 + lo;
      const float bias = b_enc[l * DT + f];
      #pragma unroll
      for (int mi = 0; mi < 2; ++mi) {
        #pragma unroll
        for (int rr = 0; rr < 4; ++rr) {
          const int n = w * 32 + mi * 16 + hi * 4 + rr;
          float v = acc[mi][ni][rr] + bias;
          v = v > 0.f ? v : 0.f;
          acts[((size_t)l * TOK + n) * DT + f] = (ushort)f2bf(v);
        }
      }
    }
    __syncthreads();
  }
}

// decode grid tables
__device__ const int SJ_[6]   = {6, 12, 16, 24, 24, 32};
__device__ const int FJ_[6]   = {1024, 512, 384, 256, 256, 192};
__device__ const int BOFF_[7] = {0, 18, 54, 102, 174, 246, 342};

// r9 decode, whole body (incl. atomic epilogue) repeated DREP times.
// acc re-zeroed per rep; epilogue adds (rep==0 ? acc+bias : 0.0f) -> identical
// per-rep memory behavior, mathematically a no-op for rep>0.
__global__ __launch_bounds__(256, 2) void decode_k(
    const ushort* __restrict__ acts, const float* __restrict__ W_dec,
    const float* __restrict__ b_dec, float* __restrict__ out)
{
  __shared__ float lw[2][32][TD];   // 64 KB

  const int bid = blockIdx.x;
  int j = 0;
  #pragma unroll
  for (int jj = 1; jj < 6; ++jj) if (bid >= BOFF_[jj]) j = jj;
  const int r  = bid - BOFF_[j];
  const int S  = SJ_[j];
  const int F  = FJ_[j];
  const int t  = r / S;
  const int sp = r % S;
  const int fb = sp * F;
  const int ns = F / 32;
  const int nv = (j + 1) * ns;

  const int w = threadIdx.x >> 6;
  const int lane = threadIdx.x & 63;
  const int lo = lane & 15, hi = lane >> 4;

  #pragma unroll 1
  for (int rep = 0; rep < DREP; ++rep) {
    f32x4 acc[8][4];
    #pragma unroll
    for (int mi = 0; mi < 8; ++mi)
      #pragma unroll
      for (int ni = 0; ni < 4; ++ni)
        acc[mi][ni] = f32x4{0.f, 0.f, 0.f, 0.f};

    {
      const float* W0 = W_dec + ((size_t)(0 * NL + j) * DT + fb) * DM + t * TD;
      #pragma unroll
      for (int q = 0; q < 8; ++q) {
        const int row = w * 8 + q;
        stage16(W0 + (size_t)row * DM + lane * 4, &lw[0][row][0]);
      }
    }
    __syncthreads();

    int cur = 0;
    int i = 0, s = 0;
    #pragma unroll 1
    for (int v = 0; v < nv; ++v) {
      int i2 = i, s2 = s + 1;
      if (s2 == ns) { s2 = 0; ++i2; }

      if (v + 1 < nv) {
        const float* Ws = W_dec + ((size_t)(i2 * NL + j) * DT + fb + s2 * 32) * DM + t * TD;
        #pragma unroll
        for (int q = 0; q < 8; ++q) {
          const int row = w * 8 + q;
          stage16(Ws + (size_t)row * DM + lane * 4, &lw[cur ^ 1][row][0]);
        }
      }

      const ushort* Av = acts + (size_t)i * TOK * DT + fb + s * 32;
      bf16x8 a[8];
      #pragma unroll
      for (int mi = 0; mi < 8; ++mi)
        a[mi] = *(const bf16x8*)(Av + (size_t)(mi * 16 + lo) * DT + hi * 8);

      bf16x8 bb[4];
      #pragma unroll
      for (int ni = 0; ni < 4; ++ni) {
        const int col = w * 64 + ni * 16 + lo;
        #pragma unroll
        for (int e = 0; e < 8; ++e)
          bb[ni][e] = f2bf(lw[cur][hi * 8 + e][col]);
      }

      #pragma unroll
      for (int mi = 0; mi < 8; ++mi)
        #pragma unroll
        for (int ni = 0; ni < 4; ++ni)
          acc[mi][ni] = __builtin_amdgcn_mfma_f32_16x16x32_bf16(a[mi], bb[ni], acc[mi][ni], 0, 0, 0);

      __syncthreads();
      cur ^= 1;
      i = i2; s = s2;
    }

    const float sc = (rep == 0) ? 1.0f : 0.0f;
    float* oj = out + (size_t)j * TOK * DM;
    #pragma unroll
    for (int ni = 0; ni < 4; ++ni) {
      const int d = t * TD + w * 64 + ni * 16 + lo;
      const float bias = (sp == 0) ? b_dec[j * DM + d] : 0.f;
      #pragma unroll
      for (int mi = 0; mi < 8; ++mi)
        #pragma unroll
        for (int rr = 0; rr < 4; ++rr)
          atomicAdd(oj + (size_t)(mi * 16 + hi * 4 + rr) * DM + d,
                    sc * (acc[mi][ni][rr] + bias));
    }
    __syncthreads();
  }
}

extern "C" void kernel_launch(void* const* d_in, const int* in_sizes, int n_in,
                              void* d_out, int out_size, void* d_ws, size_t ws_size,
                              hipStream_t stream) {
  const float* x     = (const float*)d_in[0];
  const float* W_enc = (const float*)d_in[1];
  const float* b_enc = (const float*)d_in[2];
  const float* b_dec = (const float*)d_in[3];
  const float* W_dec = (const float*)d_in[4];
  float* out = (float*)d_out;
  ushort* acts = (ushort*)d_ws;                      // 6*128*6144 bf16 = 9.44 MB
  ushort* xb   = acts + (size_t)NL * TOK * DT;       // 6*128*768 bf16 = 1.18 MB

  hipMemsetAsync(out, 0, (size_t)out_size * sizeof(float), stream);
  initcvt_k<<<dim3((NL * TOK * DM + 255) / 256), dim3(256), 0, stream>>>(x, xb);
  encode_k<<<dim3(NL * (DT / EF)), dim3(256), 0, stream>>>(xb, W_enc, b_enc, acts);
  decode_k<<<dim3(342), dim3(256), 0, stream>>>(acts, W_dec, b_dec, out);
}

// Round 14
// 242.966 us; speedup vs baseline: 9.9954x; 9.9954x over previous
//
#include <hip/hip_runtime.h>
#include <hip/hip_bf16.h>

#define NL 6
#define DT 6144
#define DM 768
#define TOK 128

// encode: r12 chassis (contiguous 1KB stage16 + 16B-chunk XOR swizzle) -- measured 33 us/rep
#define EF 32             // f-rows per block (4 waves x 8 rows staged)
#define EK 256            // k-cols per step (1 KB/row -> contiguous stage16)
#define ENST (DM / EK)    // 3 k-steps

// decode: r3/r4 chassis -- measured 62-66 us/rep (1008 blocks, uniform work)
#define TD 256            // d-tile width
#define NTD 3             // d-tiles
#define FC 384            // f-chunk
#define NFC 16            // f-chunks
#define NSTEP (FC / 32)   // 12 k-steps

using bf16x8 = __attribute__((ext_vector_type(8))) short;
using f32x4  = __attribute__((ext_vector_type(4))) float;

typedef unsigned int u32;
typedef __attribute__((address_space(1))) const u32 gu32;
typedef __attribute__((address_space(3))) u32 lu32;

// async global->LDS, 16B per lane; LDS dest = wave-uniform base + lane*16.
// RULE (r10/r13): each instruction's 64 lane addresses must form ONE contiguous
// aligned 1KB block (lane order within it is free; XOR mask <8 keeps quarters
// in their 256B sub-blocks). Violating this collapses DMA throughput ~10x.
__device__ __forceinline__ void stage16(const float* g, float* l) {
  __builtin_amdgcn_global_load_lds((gu32*)g, (lu32*)l, 16, 0, 0);
}

// round-to-nearest-even f32 -> bf16 (branchless; inputs are finite)
__device__ __forceinline__ short f2bf(float f) {
  union { float f; unsigned u; } c; c.f = f;
  unsigned u = c.u;
  u += 0x7fffu + ((u >> 16) & 1u);
  return (short)(u >> 16);
}

// out[j][n][d] = b_dec[j][d]  AND  xb = bf16(x)
__global__ void initcvt_k(const float* __restrict__ b_dec,
                          const float* __restrict__ x,
                          float* __restrict__ out, ushort* __restrict__ xb) {
  int idx = blockIdx.x * 256 + threadIdx.x;
  if (idx < NL * TOK * DM) {
    out[idx] = b_dec[(idx / (TOK * DM)) * DM + (idx % DM)];
    xb[idx] = (ushort)f2bf(x[idx]);
  }
}

// acts[l][n][f] = relu(x[l] @ W_enc[l]^T + b_enc[l]), bf16 out. r12 chassis.
// grid: 6 * 192 = 1152 blocks; 256 thr; wave w owns tok rows [w*32, w*32+32).
__global__ __launch_bounds__(256, 2) void encode_k(
    const ushort* __restrict__ xb, const float* __restrict__ W_enc,
    const float* __restrict__ b_enc, ushort* __restrict__ acts)
{
  __shared__ float lw[2][EF][EK];   // 2 x 32 KB

  const int l  = blockIdx.x / (DT / EF);
  const int f0 = (blockIdx.x % (DT / EF)) * EF;
  const int w    = threadIdx.x >> 6;        // 0..3
  const int lane = threadIdx.x & 63;
  const int lo = lane & 15, hi = lane >> 4;

  const float*  We = W_enc + ((size_t)l * DT + f0) * DM;
  const ushort* Xb = xb + (size_t)l * TOK * DM;

  f32x4 acc[2][2];
  #pragma unroll
  for (int mi = 0; mi < 2; ++mi)
    #pragma unroll
    for (int ni = 0; ni < 2; ++ni)
      acc[mi][ni] = f32x4{0.f, 0.f, 0.f, 0.f};

  // stage step 0: one contiguous (lane-permuted) 1KB row per instruction
  #pragma unroll
  for (int q = 0; q < 8; ++q) {
    const int row = w * 8 + q;
    const int g   = lane ^ (row & 7);
    stage16(We + (size_t)row * DM + g * 4, &lw[0][row][0]);
  }
  __syncthreads();

  int cur = 0;
  #pragma unroll 1
  for (int st = 0; st < ENST; ++st) {
    if (st + 1 < ENST) {
      #pragma unroll
      for (int q = 0; q < 8; ++q) {
        const int row = w * 8 + q;
        const int g   = lane ^ (row & 7);
        stage16(We + (size_t)row * DM + (st + 1) * EK + g * 4,
                &lw[cur ^ 1][row][0]);
      }
    }

    const int sw = lo & 7;
    #pragma unroll
    for (int ks = 0; ks < EK / 32; ++ks) {
      bf16x8 a[2], b[2];
      #pragma unroll
      for (int mi = 0; mi < 2; ++mi)
        a[mi] = *(const bf16x8*)(Xb + (size_t)(w * 32 + mi * 16 + lo) * DM
                                 + st * EK + ks * 32 + hi * 8);
      #pragma unroll
      for (int ni = 0; ni < 2; ++ni) {
        const int c0 = (ks * 8 + hi * 2) ^ sw;
        const int c1 = (ks * 8 + hi * 2 + 1) ^ sw;
        const float4 b0 = *(const float4*)&lw[cur][ni * 16 + lo][c0 * 4];
        const float4 b1 = *(const float4*)&lw[cur][ni * 16 + lo][c1 * 4];
        b[ni][0] = f2bf(b0.x); b[ni][1] = f2bf(b0.y);
        b[ni][2] = f2bf(b0.z); b[ni][3] = f2bf(b0.w);
        b[ni][4] = f2bf(b1.x); b[ni][5] = f2bf(b1.y);
        b[ni][6] = f2bf(b1.z); b[ni][7] = f2bf(b1.w);
      }

      #pragma unroll
      for (int mi = 0; mi < 2; ++mi)
        #pragma unroll
        for (int ni = 0; ni < 2; ++ni)
          acc[mi][ni] = __builtin_amdgcn_mfma_f32_16x16x32_bf16(a[mi], b[ni], acc[mi][ni], 0, 0, 0);
    }

    __syncthreads();
    cur ^= 1;
  }

  #pragma unroll
  for (int ni = 0; ni < 2; ++ni) {
    const int f = f0 + ni * 16 + lo;
    const float bias = b_enc[l * DT + f];
    #pragma unroll
    for (int mi = 0; mi < 2; ++mi) {
      #pragma unroll
      for (int rr = 0; rr < 4; ++rr) {
        const int n = w * 32 + mi * 16 + hi * 4 + rr;
        float v = acc[mi][ni][rr] + bias;
        v = v > 0.f ? v : 0.f;
        acts[((size_t)l * TOK + n) * DT + f] = (ushort)f2bf(v);
      }
    }
  }
}

// pair enumeration (i <= j), 21 valid decoder blocks
__device__ const int PI_[21] = {0,0,0,0,0,0, 1,1,1,1,1, 2,2,2,2, 3,3,3, 4,4, 5};
__device__ const int PJ_[21] = {0,1,2,3,4,5, 1,2,3,4,5, 2,3,4,5, 3,4,5, 4,5, 5};

// out[j] += acts[i] @ W_dec[i][j], one (i,j) pair per block (uniform work).
// r3/r4 chassis, MEASURED 62-66 us/rep + atomics. 1008 blocks -> ~4 blocks/CU
// queued (2 resident), full-chip BW. Do not shrink the grid (r13 lesson).
__global__ __launch_bounds__(256, 2) void decode_k(
    const ushort* __restrict__ acts, const float* __restrict__ W_dec,
    float* __restrict__ out)
{
  __shared__ float lw[2][32][TD];   // 64 KB

  const int bid = blockIdx.x;
  const int p  = bid / (NTD * NFC);
  const int rm = bid % (NTD * NFC);
  const int c  = rm / NTD;
  const int t  = rm % NTD;
  const int i = PI_[p], j = PJ_[p];
  const int w = threadIdx.x >> 6;
  const int lane = threadIdx.x & 63;
  const int lo = lane & 15, hi = lane >> 4;
  const int fb = c * FC;

  const float*  Wb = W_dec + ((size_t)(i * NL + j) * DT + fb) * DM + t * TD;
  const ushort* Ab = acts + (size_t)i * TOK * DT + fb;

  f32x4 acc[8][4];
  #pragma unroll
  for (int mi = 0; mi < 8; ++mi)
    #pragma unroll
    for (int ni = 0; ni < 4; ++ni)
      acc[mi][ni] = f32x4{0.f, 0.f, 0.f, 0.f};

  #pragma unroll
  for (int q = 0; q < 8; ++q) {
    const int row = w * 8 + q;
    stage16(Wb + (size_t)row * DM + lane * 4, &lw[0][row][0]);
  }
  __syncthreads();

  int cur = 0;
  #pragma unroll 1
  for (int s = 0; s < NSTEP; ++s) {
    if (s + 1 < NSTEP) {
      const float* Ws = Wb + (size_t)(s + 1) * 32 * DM;
      #pragma unroll
      for (int q = 0; q < 8; ++q) {
        const int row = w * 8 + q;
        stage16(Ws + (size_t)row * DM + lane * 4, &lw[cur ^ 1][row][0]);
      }
    }

    bf16x8 a[8];
    #pragma unroll
    for (int mi = 0; mi < 8; ++mi)
      a[mi] = *(const bf16x8*)(Ab + (size_t)(mi * 16 + lo) * DT + s * 32 + hi * 8);

    bf16x8 bb[4];
    #pragma unroll
    for (int ni = 0; ni < 4; ++ni) {
      const int col = w * 64 + ni * 16 + lo;
      #pragma unroll
      for (int e = 0; e < 8; ++e)
        bb[ni][e] = f2bf(lw[cur][hi * 8 + e][col]);
    }

    #pragma unroll
    for (int mi = 0; mi < 8; ++mi)
      #pragma unroll
      for (int ni = 0; ni < 4; ++ni)
        acc[mi][ni] = __builtin_amdgcn_mfma_f32_16x16x32_bf16(a[mi], bb[ni], acc[mi][ni], 0, 0, 0);

    __syncthreads();
    cur ^= 1;
  }

  float* oj = out + (size_t)j * TOK * DM;
  #pragma unroll
  for (int ni = 0; ni < 4; ++ni) {
    const int d = t * TD + w * 64 + ni * 16 + lo;
    #pragma unroll
    for (int mi = 0; mi < 8; ++mi)
      #pragma unroll
      for (int rr = 0; rr < 4; ++rr)
        atomicAdd(oj + (size_t)(mi * 16 + hi * 4 + rr) * DM + d, acc[mi][ni][rr]);
  }
}

extern "C" void kernel_launch(void* const* d_in, const int* in_sizes, int n_in,
                              void* d_out, int out_size, void* d_ws, size_t ws_size,
                              hipStream_t stream) {
  const float* x     = (const float*)d_in[0];
  const float* W_enc = (const float*)d_in[1];
  const float* b_enc = (const float*)d_in[2];
  const float* b_dec = (const float*)d_in[3];
  const float* W_dec = (const float*)d_in[4];
  float* out = (float*)d_out;
  ushort* acts = (ushort*)d_ws;                      // 6*128*6144 bf16 = 9.44 MB
  ushort* xb   = acts + (size_t)NL * TOK * DT;       // 6*128*768 bf16 = 1.18 MB

  initcvt_k<<<dim3((NL * TOK * DM + 255) / 256), dim3(256), 0, stream>>>(b_dec, x, out, xb);
  encode_k<<<dim3(NL * (DT / EF)), dim3(256), 0, stream>>>(xb, W_enc, b_enc, acts);
  decode_k<<<dim3(21 * NFC * NTD), dim3(256), 0, stream>>>(acts, W_dec, out);
}

// Round 15
// 185.124 us; speedup vs baseline: 13.1185x; 1.3124x over previous
//
#include <hip/hip_runtime.h>
#include <hip/hip_bf16.h>

#define NL 6
#define DT 6144
#define DM 768
#define TOK 128

// encode: r12 chassis (contiguous 1KB stage16 + 16B-chunk XOR swizzle)
#define EF 32             // f-rows per block
#define EK 256            // k-cols per step
#define ENST (DM / EK)    // 3 k-steps

// decode partials path: 504 uniform blocks (= 2/CU resident), no atomics
#define TD 256            // d-tile width
#define NTD 3             // d-tiles
#define FC 768            // f-chunk
#define NFC 8             // f-chunks
#define NSTEP (FC / 32)   // 24 k-steps
#define TILE_ELEMS (TOK * TD)   // 32768 f32 per partial tile

// fallback (atomic) decode config = r14
#define FCA 384
#define NFCA 16
#define NSTEPA (FCA / 32)

using bf16x8 = __attribute__((ext_vector_type(8))) short;
using f32x4  = __attribute__((ext_vector_type(4))) float;

typedef unsigned int u32;
typedef __attribute__((address_space(1))) const u32 gu32;
typedef __attribute__((address_space(3))) u32 lu32;

// async global->LDS, 16B/lane; RULE (r10/r13): one contiguous aligned 1KB
// block per instruction (lane order free within it).
__device__ __forceinline__ void stage16(const float* g, float* l) {
  __builtin_amdgcn_global_load_lds((gu32*)g, (lu32*)l, 16, 0, 0);
}

__device__ __forceinline__ short f2bf(float f) {
  union { float f; unsigned u; } c; c.f = f;
  unsigned u = c.u;
  u += 0x7fffu + ((u >> 16) & 1u);
  return (short)(u >> 16);
}

// out[j][n][d] = b_dec[j][d] (for atomic fallback; overwritten by reduce_k
// in the partials path)  AND  xb = bf16(x)
__global__ void initcvt_k(const float* __restrict__ b_dec,
                          const float* __restrict__ x,
                          float* __restrict__ out, ushort* __restrict__ xb) {
  int idx = blockIdx.x * 256 + threadIdx.x;
  if (idx < NL * TOK * DM) {
    out[idx] = b_dec[(idx / (TOK * DM)) * DM + (idx % DM)];
    xb[idx] = (ushort)f2bf(x[idx]);
  }
}

// acts[l][n][f] = relu(x[l] @ W_enc[l]^T + b_enc[l]). r12 chassis, measured.
__global__ __launch_bounds__(256, 2) void encode_k(
    const ushort* __restrict__ xb, const float* __restrict__ W_enc,
    const float* __restrict__ b_enc, ushort* __restrict__ acts)
{
  __shared__ float lw[2][EF][EK];   // 2 x 32 KB

  const int l  = blockIdx.x / (DT / EF);
  const int f0 = (blockIdx.x % (DT / EF)) * EF;
  const int w    = threadIdx.x >> 6;
  const int lane = threadIdx.x & 63;
  const int lo = lane & 15, hi = lane >> 4;

  const float*  We = W_enc + ((size_t)l * DT + f0) * DM;
  const ushort* Xb = xb + (size_t)l * TOK * DM;

  f32x4 acc[2][2];
  #pragma unroll
  for (int mi = 0; mi < 2; ++mi)
    #pragma unroll
    for (int ni = 0; ni < 2; ++ni)
      acc[mi][ni] = f32x4{0.f, 0.f, 0.f, 0.f};

  #pragma unroll
  for (int q = 0; q < 8; ++q) {
    const int row = w * 8 + q;
    const int g   = lane ^ (row & 7);
    stage16(We + (size_t)row * DM + g * 4, &lw[0][row][0]);
  }
  __syncthreads();

  int cur = 0;
  #pragma unroll 1
  for (int st = 0; st < ENST; ++st) {
    if (st + 1 < ENST) {
      #pragma unroll
      for (int q = 0; q < 8; ++q) {
        const int row = w * 8 + q;
        const int g   = lane ^ (row & 7);
        stage16(We + (size_t)row * DM + (st + 1) * EK + g * 4,
                &lw[cur ^ 1][row][0]);
      }
    }

    const int sw = lo & 7;
    #pragma unroll
    for (int ks = 0; ks < EK / 32; ++ks) {
      bf16x8 a[2], b[2];
      #pragma unroll
      for (int mi = 0; mi < 2; ++mi)
        a[mi] = *(const bf16x8*)(Xb + (size_t)(w * 32 + mi * 16 + lo) * DM
                                 + st * EK + ks * 32 + hi * 8);
      #pragma unroll
      for (int ni = 0; ni < 2; ++ni) {
        const int c0 = (ks * 8 + hi * 2) ^ sw;
        const int c1 = (ks * 8 + hi * 2 + 1) ^ sw;
        const float4 b0 = *(const float4*)&lw[cur][ni * 16 + lo][c0 * 4];
        const float4 b1 = *(const float4*)&lw[cur][ni * 16 + lo][c1 * 4];
        b[ni][0] = f2bf(b0.x); b[ni][1] = f2bf(b0.y);
        b[ni][2] = f2bf(b0.z); b[ni][3] = f2bf(b0.w);
        b[ni][4] = f2bf(b1.x); b[ni][5] = f2bf(b1.y);
        b[ni][6] = f2bf(b1.z); b[ni][7] = f2bf(b1.w);
      }

      #pragma unroll
      for (int mi = 0; mi < 2; ++mi)
        #pragma unroll
        for (int ni = 0; ni < 2; ++ni)
          acc[mi][ni] = __builtin_amdgcn_mfma_f32_16x16x32_bf16(a[mi], b[ni], acc[mi][ni], 0, 0, 0);
    }

    __syncthreads();
    cur ^= 1;
  }

  #pragma unroll
  for (int ni = 0; ni < 2; ++ni) {
    const int f = f0 + ni * 16 + lo;
    const float bias = b_enc[l * DT + f];
    #pragma unroll
    for (int mi = 0; mi < 2; ++mi) {
      #pragma unroll
      for (int rr = 0; rr < 4; ++rr) {
        const int n = w * 32 + mi * 16 + hi * 4 + rr;
        float v = acc[mi][ni][rr] + bias;
        v = v > 0.f ? v : 0.f;
        acts[((size_t)l * TOK + n) * DT + f] = (ushort)f2bf(v);
      }
    }
  }
}

// pair tables: p(i,j) = OFFI_[i] + (j-i), for i<=j
__device__ const int PI_[21]  = {0,0,0,0,0,0, 1,1,1,1,1, 2,2,2,2, 3,3,3, 4,4, 5};
__device__ const int PJ_[21]  = {0,1,2,3,4,5, 1,2,3,4,5, 2,3,4,5, 3,4,5, 4,5, 5};
__device__ const int OFFI_[6] = {0, 6, 11, 15, 18, 20};

// partials path: part[((p*NFC + c)*NTD + t)][n][dl] = acts[i] @ W_dec[i][j] tile.
// Plain coalesced stores -- ZERO atomics (r14 lesson: 33M contended atomics
// ~= 130 us; this replaces them with 66 MB of streaming stores).
__global__ __launch_bounds__(256, 2) void decode_part_k(
    const ushort* __restrict__ acts, const float* __restrict__ W_dec,
    float* __restrict__ part)
{
  __shared__ float lw[2][32][TD];   // 64 KB

  const int bid = blockIdx.x;
  const int p  = bid / (NTD * NFC);
  const int rm = bid % (NTD * NFC);
  const int c  = rm / NTD;
  const int t  = rm % NTD;
  const int i = PI_[p], j = PJ_[p];
  const int w = threadIdx.x >> 6;
  const int lane = threadIdx.x & 63;
  const int lo = lane & 15, hi = lane >> 4;
  const int fb = c * FC;

  const float*  Wb = W_dec + ((size_t)(i * NL + j) * DT + fb) * DM + t * TD;
  const ushort* Ab = acts + (size_t)i * TOK * DT + fb;

  f32x4 acc[8][4];
  #pragma unroll
  for (int mi = 0; mi < 8; ++mi)
    #pragma unroll
    for (int ni = 0; ni < 4; ++ni)
      acc[mi][ni] = f32x4{0.f, 0.f, 0.f, 0.f};

  #pragma unroll
  for (int q = 0; q < 8; ++q) {
    const int row = w * 8 + q;
    stage16(Wb + (size_t)row * DM + lane * 4, &lw[0][row][0]);
  }
  __syncthreads();

  int cur = 0;
  #pragma unroll 1
  for (int s = 0; s < NSTEP; ++s) {
    if (s + 1 < NSTEP) {
      const float* Ws = Wb + (size_t)(s + 1) * 32 * DM;
      #pragma unroll
      for (int q = 0; q < 8; ++q) {
        const int row = w * 8 + q;
        stage16(Ws + (size_t)row * DM + lane * 4, &lw[cur ^ 1][row][0]);
      }
    }

    bf16x8 a[8];
    #pragma unroll
    for (int mi = 0; mi < 8; ++mi)
      a[mi] = *(const bf16x8*)(Ab + (size_t)(mi * 16 + lo) * DT + s * 32 + hi * 8);

    bf16x8 bb[4];
    #pragma unroll
    for (int ni = 0; ni < 4; ++ni) {
      const int col = w * 64 + ni * 16 + lo;
      #pragma unroll
      for (int e = 0; e < 8; ++e)
        bb[ni][e] = f2bf(lw[cur][hi * 8 + e][col]);
    }

    #pragma unroll
    for (int mi = 0; mi < 8; ++mi)
      #pragma unroll
      for (int ni = 0; ni < 4; ++ni)
        acc[mi][ni] = __builtin_amdgcn_mfma_f32_16x16x32_bf16(a[mi], bb[ni], acc[mi][ni], 0, 0, 0);

    __syncthreads();
    cur ^= 1;
  }

  float* pp = part + (size_t)bid * TILE_ELEMS;
  #pragma unroll
  for (int ni = 0; ni < 4; ++ni) {
    const int dl = w * 64 + ni * 16 + lo;
    #pragma unroll
    for (int mi = 0; mi < 8; ++mi)
      #pragma unroll
      for (int rr = 0; rr < 4; ++rr)
        pp[(size_t)(mi * 16 + hi * 4 + rr) * TD + dl] = acc[mi][ni][rr];
  }
}

// out[j][n][d] = b_dec[j][d] + sum_{i<=j} sum_c part[((p(i,j)*NFC+c)*NTD+t)][n][dl]
__global__ void reduce_k(const float* __restrict__ part,
                         const float* __restrict__ b_dec,
                         float* __restrict__ out)
{
  const int idx = blockIdx.x * 256 + threadIdx.x;
  if (idx >= NL * TOK * DM) return;
  const int j   = idx / (TOK * DM);
  const int rem = idx % (TOK * DM);
  const int n   = rem / DM;
  const int d   = rem % DM;
  const int t   = d >> 8;          // /TD
  const int dl  = d & (TD - 1);

  float s = b_dec[j * DM + d];
  for (int i = 0; i <= j; ++i) {
    const int p = OFFI_[i] + (j - i);
    const float* pb = part + ((size_t)(p * NFC) * NTD + t) * TILE_ELEMS
                      + (size_t)n * TD + dl;
    #pragma unroll
    for (int c = 0; c < NFC; ++c)
      s += pb[(size_t)c * NTD * TILE_ELEMS];
  }
  out[idx] = s;
}

// fallback: r14 atomic decode (used only if ws too small for partials)
__global__ __launch_bounds__(256, 2) void decode_atomic_k(
    const ushort* __restrict__ acts, const float* __restrict__ W_dec,
    float* __restrict__ out)
{
  __shared__ float lw[2][32][TD];

  const int bid = blockIdx.x;
  const int p  = bid / (NTD * NFCA);
  const int rm = bid % (NTD * NFCA);
  const int c  = rm / NTD;
  const int t  = rm % NTD;
  const int i = PI_[p], j = PJ_[p];
  const int w = threadIdx.x >> 6;
  const int lane = threadIdx.x & 63;
  const int lo = lane & 15, hi = lane >> 4;
  const int fb = c * FCA;

  const float*  Wb = W_dec + ((size_t)(i * NL + j) * DT + fb) * DM + t * TD;
  const ushort* Ab = acts + (size_t)i * TOK * DT + fb;

  f32x4 acc[8][4];
  #pragma unroll
  for (int mi = 0; mi < 8; ++mi)
    #pragma unroll
    for (int ni = 0; ni < 4; ++ni)
      acc[mi][ni] = f32x4{0.f, 0.f, 0.f, 0.f};

  #pragma unroll
  for (int q = 0; q < 8; ++q) {
    const int row = w * 8 + q;
    stage16(Wb + (size_t)row * DM + lane * 4, &lw[0][row][0]);
  }
  __syncthreads();

  int cur = 0;
  #pragma unroll 1
  for (int s = 0; s < NSTEPA; ++s) {
    if (s + 1 < NSTEPA) {
      const float* Ws = Wb + (size_t)(s + 1) * 32 * DM;
      #pragma unroll
      for (int q = 0; q < 8; ++q) {
        const int row = w * 8 + q;
        stage16(Ws + (size_t)row * DM + lane * 4, &lw[cur ^ 1][row][0]);
      }
    }

    bf16x8 a[8];
    #pragma unroll
    for (int mi = 0; mi < 8; ++mi)
      a[mi] = *(const bf16x8*)(Ab + (size_t)(mi * 16 + lo) * DT + s * 32 + hi * 8);

    bf16x8 bb[4];
    #pragma unroll
    for (int ni = 0; ni < 4; ++ni) {
      const int col = w * 64 + ni * 16 + lo;
      #pragma unroll
      for (int e = 0; e < 8; ++e)
        bb[ni][e] = f2bf(lw[cur][hi * 8 + e][col]);
    }

    #pragma unroll
    for (int mi = 0; mi < 8; ++mi)
      #pragma unroll
      for (int ni = 0; ni < 4; ++ni)
        acc[mi][ni] = __builtin_amdgcn_mfma_f32_16x16x32_bf16(a[mi], bb[ni], acc[mi][ni], 0, 0, 0);

    __syncthreads();
    cur ^= 1;
  }

  float* oj = out + (size_t)j * TOK * DM;
  #pragma unroll
  for (int ni = 0; ni < 4; ++ni) {
    const int d = t * TD + w * 64 + ni * 16 + lo;
    #pragma unroll
    for (int mi = 0; mi < 8; ++mi)
      #pragma unroll
      for (int rr = 0; rr < 4; ++rr)
        atomicAdd(oj + (size_t)(mi * 16 + hi * 4 + rr) * DM + d, acc[mi][ni][rr]);
  }
}

extern "C" void kernel_launch(void* const* d_in, const int* in_sizes, int n_in,
                              void* d_out, int out_size, void* d_ws, size_t ws_size,
                              hipStream_t stream) {
  const float* x     = (const float*)d_in[0];
  const float* W_enc = (const float*)d_in[1];
  const float* b_enc = (const float*)d_in[2];
  const float* b_dec = (const float*)d_in[3];
  const float* W_dec = (const float*)d_in[4];
  float* out = (float*)d_out;

  const size_t actsB = (size_t)NL * TOK * DT * 2;   // 9.44 MB
  const size_t xbB   = (size_t)NL * TOK * DM * 2;   // 1.18 MB
  const size_t partB = (size_t)21 * NFC * NTD * TILE_ELEMS * 4;   // 66 MB

  ushort* acts = (ushort*)d_ws;
  ushort* xb   = (ushort*)((char*)d_ws + actsB);
  float*  part = (float*)((char*)d_ws + actsB + xbB);

  initcvt_k<<<dim3((NL * TOK * DM + 255) / 256), dim3(256), 0, stream>>>(b_dec, x, out, xb);
  encode_k<<<dim3(NL * (DT / EF)), dim3(256), 0, stream>>>(xb, W_enc, b_enc, acts);

  if (ws_size >= actsB + xbB + partB) {
    decode_part_k<<<dim3(21 * NFC * NTD), dim3(256), 0, stream>>>(acts, W_dec, part);
    reduce_k<<<dim3((NL * TOK * DM + 255) / 256), dim3(256), 0, stream>>>(part, b_dec, out);
  } else {
    decode_atomic_k<<<dim3(21 * NFCA * NTD), dim3(256), 0, stream>>>(acts, W_dec, out);
  }
}